// Round 16
// baseline (2519.672 us; speedup 1.0000x reference)
//
#include <hip/hip_runtime.h>
#include <math.h>

#define T_STEPS 4096
#define NB 16          // batch
#define NH 256         // hidden
#define BH (NB * NH)   // 4096 floats per time step
#define DT_STEP 0.1f

typedef __attribute__((ext_vector_type(8))) short short8;
typedef __attribute__((ext_vector_type(4))) float f32x4;

// ---------------- expm via Taylor series ----------------
__global__ __launch_bounds__(1024) void k_init_S(const float* __restrict__ A,
                                                 float* __restrict__ S) {
    int idx = blockIdx.x * 1024 + threadIdx.x;
    int i = idx >> 8, j = idx & 255;
    S[idx] = A[idx] + (i == j ? 1.0f : 0.0f);
}

__global__ __launch_bounds__(256) void k_expm_term(const float* __restrict__ Pprev,
                                                   const float* __restrict__ A,
                                                   float* __restrict__ Pnew,
                                                   float* __restrict__ S,
                                                   float invk) {
    __shared__ float prow[256];
    int i = blockIdx.x, j = threadIdx.x;
    prow[j] = Pprev[i * 256 + j];
    __syncthreads();
    float acc = 0.f;
#pragma unroll 8
    for (int m = 0; m < 256; ++m) acc = fmaf(prow[m], A[m * 256 + j], acc);
    float v = acc * invk;
    Pnew[i * 256 + j] = v;
    S[i * 256 + j] += v;
}

// ---------------- pack 256x256 f32 W (row-major, n-major) into bf16 B-frag-linear ----
__global__ __launch_bounds__(64) void k_pack_b(const float* __restrict__ W,
                                               unsigned int* __restrict__ P) {
    const int f = blockIdx.x;      // 0..127
    const int l = threadIdx.x;     // 0..63
    const int n  = ((f >> 3) << 4) | (l & 15);
    const int k0 = ((f & 7) << 5) | ((l >> 4) << 3);
    const float* sp = W + n * 256 + k0;
    unsigned int o0, o1, o2, o3;
    asm volatile("v_cvt_pk_bf16_f32 %0, %1, %2" : "=v"(o0) : "v"(sp[0]), "v"(sp[1]));
    asm volatile("v_cvt_pk_bf16_f32 %0, %1, %2" : "=v"(o1) : "v"(sp[2]), "v"(sp[3]));
    asm volatile("v_cvt_pk_bf16_f32 %0, %1, %2" : "=v"(o2) : "v"(sp[4]), "v"(sp[5]));
    asm volatile("v_cvt_pk_bf16_f32 %0, %1, %2" : "=v"(o3) : "v"(sp[6]), "v"(sp[7]));
    uint4* dst = (uint4*)(P + ((size_t)f * 64 + l) * 4);
    *dst = make_uint4(o0, o1, o2, o3);
}

// ---------------- MFMA GEMM: C[M x 256] = A[M x 256] @ W^T + bias (unchanged) ----------------
__global__ __launch_bounds__(256) void k_gemm_mfma(const float* A,   // no restrict: may alias C
                                                   const unsigned int* __restrict__ P,
                                                   const float* __restrict__ bias,
                                                   float* C) {
    const int tid = threadIdx.x;
    const int w = tid >> 6, l = tid & 63;
    const size_t r0 = (size_t)blockIdx.x * 64 + w * 16;
    const int arow = l & 15;
    const int kg   = l >> 4;

    union Frag { unsigned int u[4]; uint4 q; short8 v; };

    Frag af[8];
    const float* ap = A + (r0 + arow) * 256 + kg * 8;
#pragma unroll
    for (int kt = 0; kt < 8; ++kt) {
        float4 x0 = *(const float4*)(ap + kt * 32);
        float4 x1 = *(const float4*)(ap + kt * 32 + 4);
        asm volatile("v_cvt_pk_bf16_f32 %0, %1, %2" : "=v"(af[kt].u[0]) : "v"(x0.x), "v"(x0.y));
        asm volatile("v_cvt_pk_bf16_f32 %0, %1, %2" : "=v"(af[kt].u[1]) : "v"(x0.z), "v"(x0.w));
        asm volatile("v_cvt_pk_bf16_f32 %0, %1, %2" : "=v"(af[kt].u[2]) : "v"(x1.x), "v"(x1.y));
        asm volatile("v_cvt_pk_bf16_f32 %0, %1, %2" : "=v"(af[kt].u[3]) : "v"(x1.z), "v"(x1.w));
    }

    f32x4 acc[16];
#pragma unroll
    for (int nt = 0; nt < 16; ++nt) acc[nt] = f32x4{0.f, 0.f, 0.f, 0.f};

#pragma unroll
    for (int nt = 0; nt < 16; ++nt) {
#pragma unroll
        for (int kt = 0; kt < 8; ++kt) {
            Frag bf_;
            bf_.q = *(const uint4*)(P + (size_t)(((nt << 3) | kt) * 64 + l) * 4);
            acc[nt] = __builtin_amdgcn_mfma_f32_16x16x32_bf16(af[kt].v, bf_.v, acc[nt], 0, 0, 0);
        }
    }

#pragma unroll
    for (int nt = 0; nt < 16; ++nt) {
        float b = bias[(nt << 4) | arow];
        float* cp = C + (r0 + kg * 4) * 256 + (nt << 4) + arow;
#pragma unroll
        for (int r = 0; r < 4; ++r)
            cp[(size_t)r * 256] = acc[nt][r] + b;
    }
}

// ---------------- MFMA scan v8: 4 waves, 16 short chains, half the LDS traffic ----------------
// Model (fits r9-r14): step ~ max(LDS-pipe, chain-latency) + ~300 fixed.
// 8 waves x 8 ds_read_b128 = 768 pipe-cyc dominated r10-r14 (~12cyc/b128, m134).
// 4 waves halves that (384); r9's 4-wave failure was its 4 DEPTH-8 chains
// (latency-bound) -- here 4 nt x 4 accs = 16 depth-2 chains per wave.
// Wave w owns n-tiles 4w..4w+3; every lane owns exactly 1 h element:
// n_own = w<<6 | j_own<<4 | lg<<2 | (l&3), j_own=(l>>2)&3. 8-step VMEM
// batching kept (r14, -130us). One __syncthreads per step.
__global__ __launch_bounds__(256)
__attribute__((amdgpu_waves_per_eu(1, 1)))
void k_scan_bc7(const float* __restrict__ u,
                const float* S,        // Wexp (f32); no restrict
                float* hidden,
                float* __restrict__ hfin) {
    const int b   = blockIdx.x;
    const int tid = threadIdx.x;
    const int w   = tid >> 6;           // wave 0..3: n-tiles 4w..4w+3
    const int l   = tid & 63;
    const int lg  = l >> 4;             // k-group 0..3
    const int lr  = l & 15;             // row within n-tile

    __shared__ unsigned int hlds[256];  // 2 x 512B: h as bf16, linear, dbuf
    char* lds = (char*)hlds;

    union Frag { unsigned int u[4]; short8 v; };

    // ---- A-fragments: E rows for 4 n-tiles x 8 kt = 128 VGPRs ----
    Frag ef[4][8];
#pragma unroll
    for (int j = 0; j < 4; ++j) {
        const int n = ((4 * w + j) << 4) | lr;
#pragma unroll
        for (int kt = 0; kt < 8; ++kt) {
            const int k0 = kt * 32 + lg * 8;
            const float* sp = S + (size_t)n * 256 + k0;
            float e[8];
#pragma unroll
            for (int q = 0; q < 8; ++q)
                e[q] = sp[q] - ((n == k0 + q) ? 1.0f : 0.0f);
#pragma unroll
            for (int r2 = 0; r2 < 4; ++r2) {
                unsigned int pk;
                asm volatile("v_cvt_pk_bf16_f32 %0, %1, %2"
                             : "=v"(pk) : "v"(e[2 * r2]), "v"(e[2 * r2 + 1]));
                ef[j][kt].u[r2] = pk;
            }
        }
    }

    // ---- per-lane owned h element (bijective over 256) ----
    const int j_own = (l >> 2) & 3;
    const int n_own = (w << 6) | (j_own << 4) | (lg << 2) | (l & 3);
    const bool wrt = ((l & 1) == 0);      // LDS writer lanes (pair leader)

    hlds[tid] = 0u;                       // zero both h buffers

    const int NBLK = T_STEPS / 8;         // 512 blocks of 8 steps
    const size_t blkstride = 8 * (size_t)BH;

    float* hst = hidden + (size_t)b * NH + n_own;
    const float* uld = u + (size_t)b * NH + n_own + blkstride;

    float ucur[8], unxt[8], hsav[8];
    {
        const float* up0 = u + (size_t)b * NH + n_own;
#pragma unroll
        for (int q = 0; q < 8; ++q) ucur[q] = up0[q * (size_t)BH];
    }
    float hval = 0.f;
    __syncthreads();

    int roff = 0;                         // byte offset of read buffer (0/512)
    for (int blk = 0; blk < NBLK; ++blk) {
#pragma unroll
        for (int s = 0; s < 8; ++s) {
            if (s == 0) {
                if (blk) {
#pragma unroll
                    for (int q = 0; q < 8; ++q) hst[q * (size_t)BH] = hsav[q];
                }
#pragma unroll
                for (int q = 0; q < 8; ++q) unxt[q] = uld[q * (size_t)BH];
            }

            // B-fragments: h broadcast (same 16B per 16-lane group), 8 reads/wave
            Frag hb[8];
#pragma unroll
            for (int kt = 0; kt < 8; ++kt)
                hb[kt].v = *(const short8*)(lds + roff + kt * 64 + lg * 16);

            // 16 independent depth-2 chains: acc[nt][q] over kt = q, q+4
            f32x4 ac[4][4];
#pragma unroll
            for (int nt = 0; nt < 4; ++nt)
#pragma unroll
                for (int q = 0; q < 4; ++q) ac[nt][q] = f32x4{0.f, 0.f, 0.f, 0.f};
#pragma unroll
            for (int q = 0; q < 4; ++q)
#pragma unroll
                for (int nt = 0; nt < 4; ++nt)
                    ac[nt][q] = __builtin_amdgcn_mfma_f32_16x16x32_bf16(
                        ef[nt][q].v, hb[q].v, ac[nt][q], 0, 0, 0);
#pragma unroll
            for (int q = 0; q < 4; ++q)
#pragma unroll
                for (int nt = 0; nt < 4; ++nt)
                    ac[nt][q] = __builtin_amdgcn_mfma_f32_16x16x32_bf16(
                        ef[nt][q + 4].v, hb[q + 4].v, ac[nt][q], 0, 0, 0);

            // combine accs per tile, select owned tile then component
            f32x4 s0 = (ac[0][0] + ac[0][1]) + (ac[0][2] + ac[0][3]);
            f32x4 s1 = (ac[1][0] + ac[1][1]) + (ac[1][2] + ac[1][3]);
            f32x4 s2 = (ac[2][0] + ac[2][1]) + (ac[2][2] + ac[2][3]);
            f32x4 s3 = (ac[3][0] + ac[3][1]) + (ac[3][2] + ac[3][3]);
            f32x4 ca = (j_own & 1) ? s1 : s0;
            f32x4 cb = (j_own & 1) ? s3 : s2;
            f32x4 cc = (j_own & 2) ? cb : ca;
            float y01 = (l & 1) ? cc[1] : cc[0];
            float y23 = (l & 1) ? cc[3] : cc[2];
            float y   = (l & 2) ? y23 : y01;

            // h += dt * tanh(u - (h + E h));  tanh(x) = 1 - 2/(e^{2x}+1)
            float xa = (ucur[s] - hval) - y;
            float E2 = __expf(2.0f * xa);
            float th = fmaf(-2.0f, __builtin_amdgcn_rcpf(E2 + 1.0f), 1.0f);
            hval = fmaf(DT_STEP, th, hval);
            hsav[s] = hval;

            // pack (n_own even, n_own+1) -> dword into next LDS buffer
            int nb = __builtin_amdgcn_mov_dpp(__float_as_int(hval), 0xB1, 0xF, 0xF, true);
            if (wrt) {
                unsigned int pk;
                asm volatile("v_cvt_pk_bf16_f32 %0, %1, %2"
                             : "=v"(pk) : "v"(hval), "v"(__int_as_float(nb)));
                *(unsigned int*)(lds + (roff ^ 512) + ((n_own >> 1) << 2)) = pk;
            }
            roff ^= 512;
            __syncthreads();
        }
#pragma unroll
        for (int q = 0; q < 8; ++q) ucur[q] = unxt[q];
        if (blk) hst += blkstride;
        if (blk <= NBLK - 3) uld += blkstride;
    }

#pragma unroll
    for (int q = 0; q < 8; ++q) hst[q * (size_t)BH] = hsav[q];
    hfin[(size_t)b * NH + n_own] = hval;
}

extern "C" void kernel_launch(void* const* d_in, const int* in_sizes, int n_in,
                              void* d_out, int out_size, void* d_ws, size_t ws_size,
                              hipStream_t stream) {
    const float* x     = (const float*)d_in[0];  // [T,B,D]
    const float* U_w   = (const float*)d_in[1];  // [H,D]
    const float* U_b   = (const float*)d_in[2];  // [H]
    const float* W_log = (const float*)d_in[3];  // [H,H]
    const float* c_w   = (const float*)d_in[4];  // [O,H]
    const float* c_b   = (const float*)d_in[5];  // [O]

    float* out    = (float*)d_out;
    float* hidden = out;                          // stage hidden in d_out, then in-place GEMM
    float* hfin   = out + (long)T_STEPS * BH;     // second output chunk

    float* ws = (float*)d_ws;
    float* S  = ws;                // 65536 floats: Wexp accumulator
    float* Pa = ws + 65536;        // expm scratch; reused as packed U_w (bf16 frags)
    float* Pb = ws + 2 * 65536;    // expm scratch; reused as packed c_w (bf16 frags)
    float* u  = ws + 3 * 65536;    // 16,777,216 floats

    // Wexp = expm(W_log), Taylor K=9 (||W_log||_2 ~ 0.32 -> remainder ~1e-9)
    k_init_S<<<64, 1024, 0, stream>>>(W_log, S);
    const float* prev = W_log;
    float* cur = Pa;
    for (int k = 2; k <= 9; ++k) {
        k_expm_term<<<256, 256, 0, stream>>>(prev, W_log, cur, S, 1.0f / (float)k);
        prev = cur;
        cur = (cur == Pa) ? Pb : Pa;
    }

    // pack weights into bf16 B-frag-linear layout (Pa/Pb are dead after expm)
    unsigned int* PUw = (unsigned int*)Pa;
    unsigned int* Pcw = (unsigned int*)Pb;
    k_pack_b<<<128, 64, 0, stream>>>(U_w, PUw);
    k_pack_b<<<128, 64, 0, stream>>>(c_w, Pcw);

    // u = x @ U_w^T + U_b   (bf16 MFMA, f32 accumulate/output)
    k_gemm_mfma<<<1024, 256, 0, stream>>>(x, PUw, U_b, u);

    // sequential recurrence (4-wave, 16 short chains), hidden -> d_out
    k_scan_bc7<<<NB, 256, 0, stream>>>(u, S, hidden, hfin);

    // out = hidden @ c_w^T + c_b, in place (bf16 MFMA)
    k_gemm_mfma<<<1024, 256, 0, stream>>>(hidden, Pcw, c_b, hidden);
}